// Round 11
// baseline (874.043 us; speedup 1.0000x reference)
//
#include <hip/hip_runtime.h>
#include <math.h>

#define NEGF -1000000000.0f
#define EPSF 1e-7f

// B=32, T=256, IN=64, H=128, 4H=512, TOP_K=5
//
// r10 proved weights resident (VGPR 96 + 64 AGPR, WRITE_SIZE 48KB) yet
// 4900 cyc/step -> the wall is LDS instruction count + serial-phase
// latency, not weight traffic. This round: h in registers (readlane),
// serial phase replicated on all waves (kills S2 + all h-broadcast LDS),
// ballot-based candidate collection (kills LDS atomics).

#define KEEP4(v) __asm__ volatile("" : "+v"((v).x), "+v"((v).y), "+v"((v).z), "+v"((v).w))

__device__ __forceinline__ float fsigmoid(float x) {
  return 1.0f / (1.0f + __expf(-x));               // overflow -> correct limit
}
__device__ __forceinline__ float ftanh(float x) {
  return 1.0f - 2.0f / (1.0f + __expf(2.0f * x));  // limits +-1: correct
}
__device__ __forceinline__ float rlf(float v, int lane) {
  return __builtin_bit_cast(float,
      __builtin_amdgcn_readlane(__builtin_bit_cast(int, v), lane));
}

// wave64 all-reduce sum via DPP (row_shr 1/2/4/8 + row_bcast 15/31), ~35 cyc.
__device__ __forceinline__ float wave_allsum(float v) {
#if __has_builtin(__builtin_amdgcn_update_dpp) && __has_builtin(__builtin_amdgcn_readlane)
  float f = v;
#define DPPSTEP(ctrl, rmask) { \
    int t = __builtin_amdgcn_update_dpp(0, __builtin_bit_cast(int, f), \
                                        ctrl, rmask, 0xf, true); \
    f += __builtin_bit_cast(float, t); }
  DPPSTEP(0x111, 0xf)   // row_shr:1
  DPPSTEP(0x112, 0xf)   // row_shr:2
  DPPSTEP(0x114, 0xf)   // row_shr:4
  DPPSTEP(0x118, 0xf)   // row_shr:8
  DPPSTEP(0x142, 0xa)   // row_bcast:15 into rows 1,3
  DPPSTEP(0x143, 0x8)   // row_bcast:31 into row 3 -> lane 63 = total
#undef DPPSTEP
  return __builtin_bit_cast(float,
      __builtin_amdgcn_readlane(__builtin_bit_cast(int, f), 63));
#else
  for (int off = 1; off < 64; off <<= 1) v += __shfl_xor(v, off, 64);
  return v;
#endif
}

// Kernel 1: xw[b][t][g] = x[b][t] . W_ih[g] + (b_ih[g]+b_hh[g])
// grid (16, 32), 512 threads, thread = gate g, 16 timesteps/block.
// x_t broadcast via readlane (1 LDS b32 per t), weights pinned in VGPRs.
__global__ __launch_bounds__(512) void xw_kernel(
    const float* __restrict__ x, const float* __restrict__ W_ih,
    const float* __restrict__ b_ih, const float* __restrict__ b_hh,
    float* __restrict__ xw)
{
  const int t0 = blockIdx.x * 16;
  const int b  = blockIdx.y;
  const int g  = threadIdx.x;
  const int l  = threadIdx.x & 63;

  __shared__ float sx[1024];                 // 16 t x 64 in, 4 KB
  {
    size_t base = (size_t)(b * 256 + t0) * 64;
    sx[g]       = x[base + g];
    sx[g + 512] = x[base + g + 512];
  }
  const float4* wr = (const float4*)(W_ih + (size_t)g * 64);
  float4 w0 = wr[0], w1 = wr[1], w2 = wr[2],  w3 = wr[3],
         w4 = wr[4], w5 = wr[5], w6 = wr[6],  w7 = wr[7],
         w8 = wr[8], w9 = wr[9], w10 = wr[10], w11 = wr[11],
         w12 = wr[12], w13 = wr[13], w14 = wr[14], w15 = wr[15];
  KEEP4(w0); KEEP4(w1); KEEP4(w2); KEEP4(w3);
  KEEP4(w4); KEEP4(w5); KEEP4(w6); KEEP4(w7);
  KEEP4(w8); KEEP4(w9); KEEP4(w10); KEEP4(w11);
  KEEP4(w12); KEEP4(w13); KEEP4(w14); KEEP4(w15);
  const float bias = b_ih[g] + b_hh[g];
  __syncthreads();

  for (int tt = 0; tt < 16; ++tt) {
    float xl = sx[tt * 64 + l];              // lane l holds x[t][l]
    float a0 = bias, a1 = 0.0f, a2 = 0.0f, a3 = 0.0f;
#define XS(j) { \
    float x0 = rlf(xl, 4*j), x1 = rlf(xl, 4*j+1); \
    float x2 = rlf(xl, 4*j+2), x3 = rlf(xl, 4*j+3); \
    a0 = fmaf(w##j.x, x0, a0); a1 = fmaf(w##j.y, x1, a1); \
    a2 = fmaf(w##j.z, x2, a2); a3 = fmaf(w##j.w, x3, a3); }
    XS(0) XS(1) XS(2) XS(3) XS(4) XS(5) XS(6) XS(7)
    XS(8) XS(9) XS(10) XS(11) XS(12) XS(13) XS(14) XS(15)
#undef XS
    xw[(size_t)(b * 256 + t0 + tt) * 512 + g] = (a0 + a1) + (a2 + a3);
  }
}

// Kernel 2: full recurrence, one block per batch element, 512 threads.
// Thread t: K-half q = t>>8, gates gA = t&255, gB = gA+256.
// gA weights: 16 pinned float4 VGPRs; gB weights: 64 AGPRs (r10-proven).
// h lives per-wave in registers: lane l of EVERY wave holds h[2l],h[2l+1];
// Phase A pulls h via v_readlane (uniform lane idx). Serial phase
// (cell/scores/gather) replicated on all 8 waves -> ONE barrier/step.
__global__
__attribute__((amdgpu_flat_work_group_size(512, 512), amdgpu_waves_per_eu(2, 2)))
void lstm_attn(
    const float* __restrict__ xw, const float* __restrict__ W_hh,
    const float* __restrict__ w_t, float* __restrict__ out)
{
  const int b   = blockIdx.x;
  const int tid = threadIdx.x;
  const int l   = tid & 63;       // lane
  const int wid = tid >> 6;
  const int p   = tid & 255;
  const int q   = tid >> 8;       // K-half 0/1 (wave-uniform)
  const int gA  = p;
  const int gB  = p + 256;
  const int hbase = q << 5;       // readlane base: lanes 32q..32q+31 hold K-half

  __shared__ float ho[257 * 128];     // fp32 h history (131584 B)
  __shared__ float sh_part[2 * 512];  // gate partials [q][gate] (4 KB)
  __shared__ float sh_d[257];         // cached tanh(h_t).w_b scores
  __shared__ int   sh_cidx[8];
  __shared__ float sh_cw[8];

  // ---- gate-A K-half: 16 named float4 = 64 arch VGPRs, pinned ----
  const float4* pA = (const float4*)(W_hh + (size_t)gA * 128 + (q << 6));
  float4 wA0 = pA[0],   wA1 = pA[1],   wA2 = pA[2],   wA3 = pA[3],
         wA4 = pA[4],   wA5 = pA[5],   wA6 = pA[6],   wA7 = pA[7],
         wA8 = pA[8],   wA9 = pA[9],   wA10 = pA[10], wA11 = pA[11],
         wA12 = pA[12], wA13 = pA[13], wA14 = pA[14], wA15 = pA[15];
  KEEP4(wA0);  KEEP4(wA1);  KEEP4(wA2);  KEEP4(wA3);
  KEEP4(wA4);  KEEP4(wA5);  KEEP4(wA6);  KEEP4(wA7);
  KEEP4(wA8);  KEEP4(wA9);  KEEP4(wA10); KEEP4(wA11);
  KEEP4(wA12); KEEP4(wA13); KEEP4(wA14); KEEP4(wA15);

  // ---- gate-B K-half: 64 floats parked in AGPRs ----
  const float4* pB = (const float4*)(W_hh + (size_t)gB * 128 + (q << 6));
  float Ax0, Ay0, Az0, Aw0,   Ax1, Ay1, Az1, Aw1,
        Ax2, Ay2, Az2, Aw2,   Ax3, Ay3, Az3, Aw3,
        Ax4, Ay4, Az4, Aw4,   Ax5, Ay5, Az5, Aw5,
        Ax6, Ay6, Az6, Aw6,   Ax7, Ay7, Az7, Aw7,
        Ax8, Ay8, Az8, Aw8,   Ax9, Ay9, Az9, Aw9,
        Ax10, Ay10, Az10, Aw10, Ax11, Ay11, Az11, Aw11,
        Ax12, Ay12, Az12, Aw12, Ax13, Ay13, Az13, Aw13,
        Ax14, Ay14, Az14, Aw14, Ax15, Ay15, Az15, Aw15;
#define PARK4(j) { float4 tv = pB[j]; \
  __asm__ volatile("v_accvgpr_write_b32 %0, %1" : "=a"(Ax##j) : "v"(tv.x)); \
  __asm__ volatile("v_accvgpr_write_b32 %0, %1" : "=a"(Ay##j) : "v"(tv.y)); \
  __asm__ volatile("v_accvgpr_write_b32 %0, %1" : "=a"(Az##j) : "v"(tv.z)); \
  __asm__ volatile("v_accvgpr_write_b32 %0, %1" : "=a"(Aw##j) : "v"(tv.w)); }
  PARK4(0)  PARK4(1)  PARK4(2)  PARK4(3)
  PARK4(4)  PARK4(5)  PARK4(6)  PARK4(7)
  PARK4(8)  PARK4(9)  PARK4(10) PARK4(11)
  PARK4(12) PARK4(13) PARK4(14) PARK4(15)
#undef PARK4

  // ---- per-lane replicated state (EVERY wave): h elems j0=2l, j1=2l+1 ----
  const int j0 = 2 * l, j1 = 2 * l + 1;
  float hn0 = 0.0f, hn1 = 0.0f;        // h(-1) = 0
  float c0 = 0.0f, c1 = 0.0f;
  float wa0 = w_t[j0], wa1 = w_t[j1];
  float wb0 = w_t[128 + j0], wb1 = w_t[128 + j1];
  float t5_0 = 0.0f, t5_1 = NEGF, t5_2 = NEGF, t5_3 = NEGF, t5_4 = NEGF;
  if (wid == 0) {
    ho[j0] = 0.0f; ho[j1] = 0.0f;      // history row 0
    if (l == 0) sh_d[0] = 0.0f;
  }
  __syncthreads();

  const float* xwb = xw + (size_t)b * 256 * 512;
  float xcurA = 0.0f, xcurB = 0.0f;
  if (q == 0) { xcurA = xwb[gA]; xcurB = xwb[gB]; }   // step-0 prefetch

  for (int i = 0; i < 256; ++i) {
    const int rem = i + 1;

    // ---- Phase A: gate partials; h via readlane from own wave's regs ----
    float aA0 = xcurA, aA1 = 0.0f, aA2 = 0.0f, aA3 = 0.0f;
    float aB0 = xcurB, aB1 = 0.0f, aB2 = 0.0f, aB3 = 0.0f;
    if (q == 0 && i < 255) {          // prefetch next step's xw
      xcurA = xwb[(size_t)(i + 1) * 512 + gA];
      xcurB = xwb[(size_t)(i + 1) * 512 + gB];
    }
#define ASTEP(j) { \
    float h0a = rlf(hn0, hbase + 2*j),     h1a = rlf(hn1, hbase + 2*j); \
    float h0b = rlf(hn0, hbase + 2*j + 1), h1b = rlf(hn1, hbase + 2*j + 1); \
    float u0, u1, u2, u3; \
    __asm__ volatile("v_accvgpr_read_b32 %0, %1" : "=v"(u0) : "a"(Ax##j)); \
    __asm__ volatile("v_accvgpr_read_b32 %0, %1" : "=v"(u1) : "a"(Ay##j)); \
    __asm__ volatile("v_accvgpr_read_b32 %0, %1" : "=v"(u2) : "a"(Az##j)); \
    __asm__ volatile("v_accvgpr_read_b32 %0, %1" : "=v"(u3) : "a"(Aw##j)); \
    aA0 = fmaf(wA##j.x, h0a, aA0); aA1 = fmaf(wA##j.y, h1a, aA1); \
    aA2 = fmaf(wA##j.z, h0b, aA2); aA3 = fmaf(wA##j.w, h1b, aA3); \
    aB0 = fmaf(u0, h0a, aB0); aB1 = fmaf(u1, h1a, aB1); \
    aB2 = fmaf(u2, h0b, aB2); aB3 = fmaf(u3, h1b, aB3); }
    ASTEP(0)  ASTEP(1)  ASTEP(2)  ASTEP(3)
    ASTEP(4)  ASTEP(5)  ASTEP(6)  ASTEP(7)
    ASTEP(8)  ASTEP(9)  ASTEP(10) ASTEP(11)
    ASTEP(12) ASTEP(13) ASTEP(14) ASTEP(15)
#undef ASTEP
    sh_part[(q << 9) + gA] = (aA0 + aA1) + (aA2 + aA3);
    sh_part[(q << 9) + gB] = (aB0 + aB1) + (aB2 + aB3);
    __syncthreads();                                      // S1 (the only barrier)

    // ---- Serial phase: REPLICATED on every wave (identical arithmetic) ----
    float d0 = sh_d[l], d1 = sh_d[l + 64],
          d2 = sh_d[l + 128], d3 = sh_d[l + 192];

    float2 Pi0 = ((const float2*)(sh_part      ))[l];
    float2 Pi1 = ((const float2*)(sh_part + 512))[l];
    float2 Pf0 = ((const float2*)(sh_part + 128))[l];
    float2 Pf1 = ((const float2*)(sh_part + 640))[l];
    float2 Pg0 = ((const float2*)(sh_part + 256))[l];
    float2 Pg1 = ((const float2*)(sh_part + 768))[l];
    float2 Po0 = ((const float2*)(sh_part + 384))[l];
    float2 Po1 = ((const float2*)(sh_part + 896))[l];
    float gi0 = Pi0.x + Pi1.x, gi1 = Pi0.y + Pi1.y;
    float gf0 = Pf0.x + Pf1.x, gf1 = Pf0.y + Pf1.y;
    float gg0 = Pg0.x + Pg1.x, gg1 = Pg0.y + Pg1.y;
    float go0 = Po0.x + Po1.x, go1 = Po0.y + Po1.y;
    c0 = fsigmoid(gf0) * c0 + fsigmoid(gi0) * ftanh(gg0);
    c1 = fsigmoid(gf1) * c1 + fsigmoid(gi1) * ftanh(gg1);
    float hc0 = fsigmoid(go0) * ftanh(c0);
    float hc1 = fsigmoid(go1) * ftanh(c1);
    const float a = wave_allsum(ftanh(hc0) * wa0 + ftanh(hc1) * wa1);

    // scores at t = l, l+64, l+128, l+192
    const float delta = (a + t5_4) + EPSF;
    float s0 = a + d0, s1 = a + d1, s2 = a + d2, s3 = a + d3;
    float w0 = s0 - delta; w0 = (w0 > 0.0f) ? w0 : 0.0f;
    float w1 = s1 - delta; w1 = (w1 > 0.0f) ? w1 : 0.0f;
    float w2 = s2 - delta; w2 = (w2 > 0.0f) ? w2 : 0.0f;
    float w3 = s3 - delta; w3 = (w3 > 0.0f) ? w3 : 0.0f;
    const bool v0 = (l       < rem), v1 = (l + 64  < rem),
               v2 = (l + 128 < rem), v3 = (l + 192 < rem);
    float wv0 = v0 ? w0 : 0.0f, wv1 = v1 ? w1 : 0.0f,
          wv2 = v2 ? w2 : 0.0f, wv3 = v3 ? w3 : 0.0f;
    const bool small = (rem <= 5);
    bool sel0 = v0 && (small || (w0 > 0.0f));
    bool sel1 = v1 && (small || (w1 > 0.0f));
    bool sel2 = v2 && (small || (w2 > 0.0f));
    bool sel3 = v3 && (small || (w3 > 0.0f));
    float cv0 = small ? s0 : w0, cv1 = small ? s1 : w1,
          cv2 = small ? s2 : w2, cv3 = small ? s3 : w3;

    // ballot-based candidate slots (no atomics)
    unsigned long long m0 = __ballot(sel0), m1 = __ballot(sel1),
                       m2 = __ballot(sel2), m3 = __ballot(sel3);
    int b1c = __popcll(m0), b2c = b1c + __popcll(m1), b3c = b2c + __popcll(m2);
    int nz  = b3c + __popcll(m3);
    unsigned long long lt = (1ull << l) - 1ull;
    if (sel0) { int s = __popcll(m0 & lt);       if (s < 8) { sh_cidx[s] = l;       sh_cw[s] = cv0; } }
    if (sel1) { int s = b1c + __popcll(m1 & lt); if (s < 8) { sh_cidx[s] = l + 64;  sh_cw[s] = cv1; } }
    if (sel2) { int s = b2c + __popcll(m2 & lt); if (s < 8) { sh_cidx[s] = l + 128; sh_cw[s] = cv2; } }
    if (sel3) { int s = b3c + __popcll(m3 & lt); if (s < 8) { sh_cidx[s] = l + 192; sh_cw[s] = cv3; } }
    if (l >= nz && l < 8) { sh_cidx[l] = 0; sh_cw[l] = 0.0f; }  // pad (disjoint)

    float wsum = wave_allsum(wv0 + wv1 + wv2 + wv3);
    const float inv = small ? 1.0f : 1.0f / (wsum + EPSF);
    if (i == 255 && wid == 0) {                          // final attn_w
      out[4096 + b * 256 + l      ] = wv0 * inv;
      out[4096 + b * 256 + l + 64 ] = wv1 * inv;
      out[4096 + b * 256 + l + 128] = wv2 * inv;
      out[4096 + b * 256 + l + 192] = wv3 * inv;
    }

    // fixed-5 gather (nz<=5; padded slots weight 0 -> row 0, harmless)
    int   i0 = sh_cidx[0], i1 = sh_cidx[1], i2 = sh_cidx[2],
          i3 = sh_cidx[3], i4 = sh_cidx[4];
    float g0 = sh_cw[0], g1 = sh_cw[1], g2 = sh_cw[2],
          g3 = sh_cw[3], g4 = sh_cw[4];
    float at0 = g0 * ho[i0 * 128 + j0];
    float at1 = g0 * ho[i0 * 128 + j1];
    at0 = fmaf(g1, ho[i1 * 128 + j0], at0);
    at1 = fmaf(g1, ho[i1 * 128 + j1], at1);
    at0 = fmaf(g2, ho[i2 * 128 + j0], at0);
    at1 = fmaf(g2, ho[i2 * 128 + j1], at1);
    at0 = fmaf(g3, ho[i3 * 128 + j0], at0);
    at1 = fmaf(g3, ho[i3 * 128 + j1], at1);
    at0 = fmaf(g4, ho[i4 * 128 + j0], at0);
    at1 = fmaf(g4, ho[i4 * 128 + j1], at1);
    at0 *= inv; at1 *= inv;
    hn0 = hc0 + at0; hn1 = hc1 + at1;
    if (wid == 0) {
      ho[rem * 128 + j0] = hn0;
      ho[rem * 128 + j1] = hn1;
      if (i == 255) { out[b * 128 + j0] = at0; out[b * 128 + j1] = at1; }
    }
    float dn = wave_allsum(ftanh(hn0) * wb0 + ftanh(hn1) * wb1);
    if (wid == 0 && l == 0) sh_d[rem] = dn;
    // replicated top-5 insert (identical in every lane of every wave)
    float v = dn;
    if (v > t5_0) { float t = t5_0; t5_0 = v; v = t; }
    if (v > t5_1) { float t = t5_1; t5_1 = v; v = t; }
    if (v > t5_2) { float t = t5_2; t5_2 = v; v = t; }
    if (v > t5_3) { float t = t5_3; t5_3 = v; v = t; }
    if (v > t5_4) { t5_4 = v; }
    // no S2: h is in-wave registers; cross-step LDS uses are separated
    // by the NEXT iteration's S1 barrier.
  }
}

extern "C" void kernel_launch(void* const* d_in, const int* in_sizes, int n_in,
                              void* d_out, int out_size, void* d_ws, size_t ws_size,
                              hipStream_t stream) {
  const float* x    = (const float*)d_in[0];  // (32,256,64)
  const float* W_ih = (const float*)d_in[1];  // (512,64)
  const float* W_hh = (const float*)d_in[2];  // (512,128)
  const float* b_ih = (const float*)d_in[3];  // (512,)
  const float* b_hh = (const float*)d_in[4];  // (512,)
  const float* w_t  = (const float*)d_in[5];  // (256,1)
  float* out = (float*)d_out;                 // [0:4096) attn_c, [4096:12288) attn_w

  float* xw = (float*)d_ws;                   // 32*256*512 fp32 = 16 MB

  xw_kernel<<<dim3(16, 32), 512, 0, stream>>>(x, W_ih, b_ih, b_hh, xw);
  lstm_attn<<<dim3(32), 512, 0, stream>>>(xw, W_hh, w_t, out);
}